// Round 13
// baseline (62.539 us; speedup 1.0000x reference)
//
#include <hip/hip_runtime.h>
#include <hip/hip_cooperative_groups.h>
#include <math.h>

#define BB 16
#define PP 2048
#define EPSF 1e-8f
#define SCALE (1.0f / (BB * PP))

typedef _Float16 half8 __attribute__((ext_vector_type(8)));
typedef float floatx16 __attribute__((ext_vector_type(16)));

union alignas(16) Pack16 { _Float16 h[16]; float4 v[2]; };

static __device__ __forceinline__ void split16(float x, _Float16& hi, _Float16& lo) {
  hi = (_Float16)x;
  lo = (_Float16)(x - (float)hi);
}

// ---------------- Pair body: MFMA pairwise min (verified in R12) ----------
// grid = 512: blk = db(5b)*16 + rowgroup(4b). block = 256 thr = 4 waves.
// Block owns 128 rows (4 strips of 32) x ALL 2048 cols of one (b,dir).
// d^2 = a.Q + qw + aw with Q=-2q, computed exactly (~2^-22) in ONE
// mfma_f32_32x32x16_f16 via K-slot split (A/B slot positions identical ->
// k-map invariant; C orientation irrelevant: dir0+dir1 transpose-symmetric,
// min-then-sum only). LDS frags XOR-swizzled on both sides.
static __device__ __forceinline__ void pair_body(
    const float* __restrict__ R_t, const float* __restrict__ t_t,
    const float* __restrict__ R_p, const float* __restrict__ t_p,
    const float* __restrict__ mp, float* __restrict__ partial) {
  __shared__ __align__(16) _Float16 Apack[128 * 16];  // 4 KB
  __shared__ __align__(16) _Float16 Bpack[256 * 16];  // 8 KB
  __shared__ float bsum[8];
  int blk = blockIdx.x;
  int t = threadIdx.x;
  int rg = blk & 15;
  int db = blk >> 4;  // 0..31
  int dir = db & 1, b = db >> 1;
  const float* Rr = (dir ? R_p : R_t) + b * 9;
  const float* trv = (dir ? t_p : t_t) + b * 3;
  const float* Rc = (dir ? R_t : R_p) + b * 9;
  const float* tcv = (dir ? t_t : t_p) + b * 3;

  // --- pack this block's 128 rows (A side) ---
  if (t < 128) {
    int ri = (b << 11) + (rg << 7) + t;
    float x = mp[ri * 3], y = mp[ri * 3 + 1], z = mp[ri * 3 + 2];
    float axf = fmaf(Rr[0], x, fmaf(Rr[1], y, fmaf(Rr[2], z, trv[0])));
    float ayf = fmaf(Rr[3], x, fmaf(Rr[4], y, fmaf(Rr[5], z, trv[1])));
    float azf = fmaf(Rr[6], x, fmaf(Rr[7], y, fmaf(Rr[8], z, trv[2])));
    float awf = fmaf(axf, axf, fmaf(ayf, ayf, azf * azf));
    _Float16 hx, lx, hy, ly, hz, lz, hw, lw;
    split16(axf, hx, lx); split16(ayf, hy, ly); split16(azf, hz, lz);
    split16(awf, hw, lw);
    Pack16 pk;
    pk.h[0] = hx;  pk.h[1] = hy;  pk.h[2] = hz;
    pk.h[3] = hx;  pk.h[4] = hy;  pk.h[5] = hz;
    pk.h[6] = lx;  pk.h[7] = ly;  pk.h[8] = lz;
    pk.h[9] = (_Float16)1.0f; pk.h[10] = (_Float16)1.0f;
    pk.h[11] = hw; pk.h[12] = lw;
    pk.h[13] = (_Float16)0.0f; pk.h[14] = (_Float16)0.0f; pk.h[15] = (_Float16)0.0f;
    int xr = (t >> 2) & 1;
    *(float4*)&Apack[(((t << 1) | 0) ^ xr) * 8] = pk.v[0];
    *(float4*)&Apack[(((t << 1) | 1) ^ xr) * 8] = pk.v[1];
  }

  // prefetch chunk 0 col point
  float ncx, ncy, ncz;
  { int ci = (b << 11) + t; ncx = mp[ci * 3]; ncy = mp[ci * 3 + 1]; ncz = mp[ci * 3 + 2]; }

  __syncthreads();

  int lane = t & 63;
  int wv = t >> 6;        // wave -> 32-row strip
  int cl = lane & 31;
  int g = lane >> 5;      // k-group 0/1 (slots g*8..g*8+7)
  int xorb = (cl >> 2) & 1;
  int rl = (wv << 5) + cl;
  const half8 a_frag = *(const half8*)&Apack[((((rl << 1) | g)) ^ xorb) * 8];
  const _Float16* bbase = &Bpack[(((cl << 1) | g) ^ xorb) * 8];

  float m[16];
#pragma unroll
  for (int r = 0; r < 16; ++r) m[r] = 3.0e38f;
  floatx16 zacc = {};

  for (int c = 0; c < 8; ++c) {
    // pack this chunk's col (1/thread) from prefetched regs (B side)
    {
      float qx = fmaf(Rc[0], ncx, fmaf(Rc[1], ncy, fmaf(Rc[2], ncz, tcv[0])));
      float qy = fmaf(Rc[3], ncx, fmaf(Rc[4], ncy, fmaf(Rc[5], ncz, tcv[1])));
      float qz = fmaf(Rc[6], ncx, fmaf(Rc[7], ncy, fmaf(Rc[8], ncz, tcv[2])));
      float qw = fmaf(qx, qx, fmaf(qy, qy, qz * qz));
      float Qx = -2.f * qx, Qy = -2.f * qy, Qz = -2.f * qz;
      _Float16 hx, lx, hy, ly, hz, lz, hw, lw;
      split16(Qx, hx, lx); split16(Qy, hy, ly); split16(Qz, hz, lz);
      split16(qw, hw, lw);
      Pack16 pk;
      pk.h[0] = hx;  pk.h[1] = hy;  pk.h[2] = hz;
      pk.h[3] = lx;  pk.h[4] = ly;  pk.h[5] = lz;
      pk.h[6] = hx;  pk.h[7] = hy;  pk.h[8] = hz;
      pk.h[9] = hw;  pk.h[10] = lw;
      pk.h[11] = (_Float16)1.0f; pk.h[12] = (_Float16)1.0f;
      pk.h[13] = (_Float16)0.0f; pk.h[14] = (_Float16)0.0f; pk.h[15] = (_Float16)0.0f;
      int xr = (t >> 2) & 1;
      *(float4*)&Bpack[(((t << 1) | 0) ^ xr) * 8] = pk.v[0];
      *(float4*)&Bpack[(((t << 1) | 1) ^ xr) * 8] = pk.v[1];
    }
    __syncthreads();  // B ready
    if (c < 7) {      // prefetch next chunk under compute
      int ci = (b << 11) + ((c + 1) << 8) + t;
      ncx = mp[ci * 3]; ncy = mp[ci * 3 + 1]; ncz = mp[ci * 3 + 2];
    }
#pragma unroll
    for (int ct = 0; ct < 8; ct += 2) {
      half8 b0 = *(const half8*)(bbase + ct * 512);        // +1024B/tile, swizzle-consistent
      half8 b1 = *(const half8*)(bbase + (ct + 1) * 512);
      floatx16 acc0 = __builtin_amdgcn_mfma_f32_32x32x16_f16(a_frag, b0, zacc, 0, 0, 0);
      floatx16 acc1 = __builtin_amdgcn_mfma_f32_32x32x16_f16(a_frag, b1, zacc, 0, 0, 0);
#pragma unroll
      for (int r = 0; r < 16; ++r)
        m[r] = fminf(fminf(m[r], acc0[r]), acc1[r]);       // v_min3_f32
    }
    __syncthreads();  // chunk consumed
  }

  // min across the 32 lanes sharing g (bits 0..4) -> per-(hi,reg) row mins
#pragma unroll
  for (int mask = 1; mask <= 16; mask <<= 1)
#pragma unroll
    for (int r = 0; r < 16; ++r) m[r] = fminf(m[r], __shfl_xor(m[r], mask, 64));

  float s = 0.f;
#pragma unroll
  for (int r = 0; r < 16; ++r) s += sqrtf(fmaxf(m[r], 0.f) + EPSF);
  if (cl == 0) bsum[(wv << 1) | g] = s;
  __syncthreads();
  if (t == 0) {
    float tot = 0.f;
#pragma unroll
    for (int i = 0; i < 8; ++i) tot += bsum[i];
    partial[blk] = tot * SCALE;
  }
}

// ---------------- Cooperative single-dispatch version ----------------
__global__ __launch_bounds__(256) void pair_mfma_coop_kernel(
    const float* __restrict__ R_t, const float* __restrict__ t_t,
    const float* __restrict__ R_p, const float* __restrict__ t_p,
    const float* __restrict__ mp, float* __restrict__ partial,
    float* __restrict__ out) {
  pair_body(R_t, t_t, R_p, t_p, mp, partial);
  cooperative_groups::this_grid().sync();
  if (blockIdx.x == 0) {
    int t = threadIdx.x;
    float v = partial[t] + partial[t + 256];
    for (int off = 32; off; off >>= 1) v += __shfl_down(v, off, 64);
    __shared__ float ws4[4];
    if ((t & 63) == 0) ws4[t >> 6] = v;
    __syncthreads();
    if (t == 0) out[0] = ws4[0] + ws4[1] + ws4[2] + ws4[3];
  }
}

// ---------------- Classic 2-dispatch fallback (R12-proven) ----------------
__global__ __launch_bounds__(256) void pair_mfma_kernel(
    const float* __restrict__ R_t, const float* __restrict__ t_t,
    const float* __restrict__ R_p, const float* __restrict__ t_p,
    const float* __restrict__ mp, float* __restrict__ partial) {
  pair_body(R_t, t_t, R_p, t_p, mp, partial);
}

__global__ __launch_bounds__(256) void finish_kernel(
    const float* __restrict__ partial, float* __restrict__ out) {
  int t = threadIdx.x;
  float v = partial[t] + partial[t + 256];
  for (int off = 32; off; off >>= 1) v += __shfl_down(v, off, 64);
  __shared__ float ws4[4];
  if ((t & 63) == 0) ws4[t >> 6] = v;
  __syncthreads();
  if (t == 0) out[0] = ws4[0] + ws4[1] + ws4[2] + ws4[3];
}

// ---------------- Fallback (tiny ws): self-contained, no scratch ------------
__global__ __launch_bounds__(256) void fallback_kernel(
    const float* __restrict__ R_t, const float* __restrict__ t_t,
    const float* __restrict__ R_p, const float* __restrict__ t_p,
    const float* __restrict__ mp, float* __restrict__ out) {
  __shared__ float4 lds[PP];  // 32 KB
  int blk = blockIdx.x;
  int rc  = blk & 7;
  int dir = (blk >> 3) & 1;
  int b   = blk >> 4;
  const float* Rr = (dir ? R_p : R_t) + b * 9;
  const float* tr_ = (dir ? t_p : t_t) + b * 3;
  const float* Rc = (dir ? R_t : R_p) + b * 9;
  const float* tcp = (dir ? t_t : t_p) + b * 3;
  float c0 = Rc[0], c1 = Rc[1], c2 = Rc[2], c3 = Rc[3], c4 = Rc[4],
        c5 = Rc[5], c6 = Rc[6], c7 = Rc[7], c8 = Rc[8];
  float tc0 = tcp[0], tc1 = tcp[1], tc2 = tcp[2];
  for (int j = threadIdx.x; j < PP; j += 256) {
    int gi = (b * PP + j) * 3;
    float x = mp[gi], y = mp[gi + 1], z = mp[gi + 2];
    float4 q;
    q.x = fmaf(c0, x, fmaf(c1, y, fmaf(c2, z, tc0)));
    q.y = fmaf(c3, x, fmaf(c4, y, fmaf(c5, z, tc1)));
    q.z = fmaf(c6, x, fmaf(c7, y, fmaf(c8, z, tc2)));
    q.w = 0.f;
    lds[j] = q;
  }
  __syncthreads();
  int row = rc * 256 + threadIdx.x;
  int gi = (b * PP + row) * 3;
  float x = mp[gi], y = mp[gi + 1], z = mp[gi + 2];
  float ax = fmaf(Rr[0], x, fmaf(Rr[1], y, fmaf(Rr[2], z, tr_[0])));
  float ay = fmaf(Rr[3], x, fmaf(Rr[4], y, fmaf(Rr[5], z, tr_[1])));
  float az = fmaf(Rr[6], x, fmaf(Rr[7], y, fmaf(Rr[8], z, tr_[2])));
  float m = 3.4e38f;
#pragma unroll 8
  for (int j = 0; j < PP; ++j) {
    float4 q = lds[j];
    float dx = ax - q.x, dy = ay - q.y, dz = az - q.z;
    float d = fmaf(dx, dx, fmaf(dy, dy, dz * dz));
    m = fminf(m, d);
  }
  float v = sqrtf(m + EPSF) * SCALE;
  for (int off = 32; off; off >>= 1) v += __shfl_down(v, off, 64);
  __shared__ float wsum[4];
  if ((threadIdx.x & 63) == 0) wsum[threadIdx.x >> 6] = v;
  __syncthreads();
  if (threadIdx.x == 0) atomicAdd(out, wsum[0] + wsum[1] + wsum[2] + wsum[3]);
}

extern "C" void kernel_launch(void* const* d_in, const int* in_sizes, int n_in,
                              void* d_out, int out_size, void* d_ws, size_t ws_size,
                              hipStream_t stream) {
  const float* R_t = (const float*)d_in[0];
  const float* t_t = (const float*)d_in[1];
  const float* R_p = (const float*)d_in[2];
  const float* t_p = (const float*)d_in[3];
  const float* mp  = (const float*)d_in[4];
  float* out = (float*)d_out;

  if (ws_size >= 512 * sizeof(float)) {
    float* partial = (float*)d_ws;
    void* args[] = {(void*)&R_t, (void*)&t_t, (void*)&R_p, (void*)&t_p,
                    (void*)&mp, (void*)&partial, (void*)&out};
    hipError_t e = hipLaunchCooperativeKernel(
        (const void*)pair_mfma_coop_kernel, dim3(512), dim3(256), args, 0, stream);
    if (e != hipSuccess) {
      // fallback: proven 2-dispatch path
      pair_mfma_kernel<<<512, 256, 0, stream>>>(R_t, t_t, R_p, t_p, mp, partial);
      finish_kernel<<<1, 256, 0, stream>>>(partial, out);
    }
  } else {
    hipMemsetAsync(d_out, 0, sizeof(float), stream);
    fallback_kernel<<<256, 256, 0, stream>>>(R_t, t_t, R_p, t_p, mp, out);
  }
}

// Round 14
// 27.862 us; speedup vs baseline: 2.2446x; 2.2446x over previous
//
#include <hip/hip_runtime.h>
#include <math.h>

#define BB 16
#define PP 2048
#define EPSF 1e-8f
#define SCALE (1.0f / (BB * PP))

typedef _Float16 half8 __attribute__((ext_vector_type(8)));
typedef float floatx16 __attribute__((ext_vector_type(16)));

union alignas(16) Pack16 { _Float16 h[16]; float4 v[2]; };

static __device__ __forceinline__ void split16(float x, _Float16& hi, _Float16& lo) {
  hi = (_Float16)x;
  lo = (_Float16)(x - (float)hi);
}

// ---------------- Kernel P: MFMA pairwise min + last-block reduce ----------
// grid = 512: blk = db(5b)*16 + rowgroup(4b). block = 256 thr = 4 waves.
// Block owns 128 rows (4 strips of 32) x ALL 2048 cols of one (b,dir).
// d^2 = a.Q + qw + aw with Q=-2q, computed exactly (~2^-22) in ONE
// mfma_f32_32x32x16_f16 via K-slot split (verified R12, absmax 0.0).
// Tail: agent-scope release store of block partial + epoch counter
// (old & 511 == 511 detects the 512th arrival REGARDLESS of counter start
// value -> no init needed, poison-proof, replay-proof since 2^32 % 512 == 0).
// Last block acquire-loads 512 partials, reduces in fixed order, writes out.
__global__ __launch_bounds__(256) void pair_mfma_kernel(
    const float* __restrict__ R_t, const float* __restrict__ t_t,
    const float* __restrict__ R_p, const float* __restrict__ t_p,
    const float* __restrict__ mp, float* partial, unsigned int* cnt,
    float* __restrict__ out) {
  __shared__ __align__(16) _Float16 Apack[128 * 16];  // 4 KB
  __shared__ __align__(16) _Float16 Bpack[256 * 16];  // 8 KB
  __shared__ float bsum[8];
  __shared__ int lastFlag;
  int blk = blockIdx.x;
  int t = threadIdx.x;
  int rg = blk & 15;
  int db = blk >> 4;  // 0..31
  int dir = db & 1, b = db >> 1;
  const float* Rr = (dir ? R_p : R_t) + b * 9;
  const float* trv = (dir ? t_p : t_t) + b * 3;
  const float* Rc = (dir ? R_t : R_p) + b * 9;
  const float* tcv = (dir ? t_t : t_p) + b * 3;

  // --- pack this block's 128 rows (A side) ---
  if (t < 128) {
    int ri = (b << 11) + (rg << 7) + t;
    float x = mp[ri * 3], y = mp[ri * 3 + 1], z = mp[ri * 3 + 2];
    float axf = fmaf(Rr[0], x, fmaf(Rr[1], y, fmaf(Rr[2], z, trv[0])));
    float ayf = fmaf(Rr[3], x, fmaf(Rr[4], y, fmaf(Rr[5], z, trv[1])));
    float azf = fmaf(Rr[6], x, fmaf(Rr[7], y, fmaf(Rr[8], z, trv[2])));
    float awf = fmaf(axf, axf, fmaf(ayf, ayf, azf * azf));
    _Float16 hx, lx, hy, ly, hz, lz, hw, lw;
    split16(axf, hx, lx); split16(ayf, hy, ly); split16(azf, hz, lz);
    split16(awf, hw, lw);
    Pack16 pk;
    pk.h[0] = hx;  pk.h[1] = hy;  pk.h[2] = hz;
    pk.h[3] = hx;  pk.h[4] = hy;  pk.h[5] = hz;
    pk.h[6] = lx;  pk.h[7] = ly;  pk.h[8] = lz;
    pk.h[9] = (_Float16)1.0f; pk.h[10] = (_Float16)1.0f;
    pk.h[11] = hw; pk.h[12] = lw;
    pk.h[13] = (_Float16)0.0f; pk.h[14] = (_Float16)0.0f; pk.h[15] = (_Float16)0.0f;
    int xr = (t >> 2) & 1;
    *(float4*)&Apack[(((t << 1) | 0) ^ xr) * 8] = pk.v[0];
    *(float4*)&Apack[(((t << 1) | 1) ^ xr) * 8] = pk.v[1];
  }

  // prefetch chunk 0 col point
  float ncx, ncy, ncz;
  { int ci = (b << 11) + t; ncx = mp[ci * 3]; ncy = mp[ci * 3 + 1]; ncz = mp[ci * 3 + 2]; }

  __syncthreads();

  int lane = t & 63;
  int wv = t >> 6;        // wave -> 32-row strip
  int cl = lane & 31;
  int g = lane >> 5;      // k-group 0/1 (slots g*8..g*8+7)
  int xorb = (cl >> 2) & 1;
  int rl = (wv << 5) + cl;
  const half8 a_frag = *(const half8*)&Apack[((((rl << 1) | g)) ^ xorb) * 8];
  const _Float16* bbase = &Bpack[(((cl << 1) | g) ^ xorb) * 8];

  float m[16];
#pragma unroll
  for (int r = 0; r < 16; ++r) m[r] = 3.0e38f;
  floatx16 zacc = {};

  for (int c = 0; c < 8; ++c) {
    // pack this chunk's col (1/thread) from prefetched regs (B side)
    {
      float qx = fmaf(Rc[0], ncx, fmaf(Rc[1], ncy, fmaf(Rc[2], ncz, tcv[0])));
      float qy = fmaf(Rc[3], ncx, fmaf(Rc[4], ncy, fmaf(Rc[5], ncz, tcv[1])));
      float qz = fmaf(Rc[6], ncx, fmaf(Rc[7], ncy, fmaf(Rc[8], ncz, tcv[2])));
      float qw = fmaf(qx, qx, fmaf(qy, qy, qz * qz));
      float Qx = -2.f * qx, Qy = -2.f * qy, Qz = -2.f * qz;
      _Float16 hx, lx, hy, ly, hz, lz, hw, lw;
      split16(Qx, hx, lx); split16(Qy, hy, ly); split16(Qz, hz, lz);
      split16(qw, hw, lw);
      Pack16 pk;
      pk.h[0] = hx;  pk.h[1] = hy;  pk.h[2] = hz;
      pk.h[3] = lx;  pk.h[4] = ly;  pk.h[5] = lz;
      pk.h[6] = hx;  pk.h[7] = hy;  pk.h[8] = hz;
      pk.h[9] = hw;  pk.h[10] = lw;
      pk.h[11] = (_Float16)1.0f; pk.h[12] = (_Float16)1.0f;
      pk.h[13] = (_Float16)0.0f; pk.h[14] = (_Float16)0.0f; pk.h[15] = (_Float16)0.0f;
      int xr = (t >> 2) & 1;
      *(float4*)&Bpack[(((t << 1) | 0) ^ xr) * 8] = pk.v[0];
      *(float4*)&Bpack[(((t << 1) | 1) ^ xr) * 8] = pk.v[1];
    }
    __syncthreads();  // B ready
    if (c < 7) {      // prefetch next chunk under compute
      int ci = (b << 11) + ((c + 1) << 8) + t;
      ncx = mp[ci * 3]; ncy = mp[ci * 3 + 1]; ncz = mp[ci * 3 + 2];
    }
#pragma unroll
    for (int ct = 0; ct < 8; ct += 2) {
      half8 b0 = *(const half8*)(bbase + ct * 512);        // +1024B/tile, swizzle-consistent
      half8 b1 = *(const half8*)(bbase + (ct + 1) * 512);
      floatx16 acc0 = __builtin_amdgcn_mfma_f32_32x32x16_f16(a_frag, b0, zacc, 0, 0, 0);
      floatx16 acc1 = __builtin_amdgcn_mfma_f32_32x32x16_f16(a_frag, b1, zacc, 0, 0, 0);
#pragma unroll
      for (int r = 0; r < 16; ++r)
        m[r] = fminf(fminf(m[r], acc0[r]), acc1[r]);       // v_min3_f32
    }
    __syncthreads();  // chunk consumed
  }

  // min across the 32 lanes sharing g (bits 0..4) -> per-(hi,reg) row mins
#pragma unroll
  for (int mask = 1; mask <= 16; mask <<= 1)
#pragma unroll
    for (int r = 0; r < 16; ++r) m[r] = fminf(m[r], __shfl_xor(m[r], mask, 64));

  float s = 0.f;
#pragma unroll
  for (int r = 0; r < 16; ++r) s += sqrtf(fmaxf(m[r], 0.f) + EPSF);
  if (cl == 0) bsum[(wv << 1) | g] = s;
  __syncthreads();
  if (t == 0) {
    float tot = 0.f;
#pragma unroll
    for (int i = 0; i < 8; ++i) tot += bsum[i];
    __hip_atomic_store(&partial[blk], tot * SCALE, __ATOMIC_RELEASE,
                       __HIP_MEMORY_SCOPE_AGENT);
    unsigned int old = __hip_atomic_fetch_add(cnt, 1u, __ATOMIC_ACQ_REL,
                                              __HIP_MEMORY_SCOPE_AGENT);
    lastFlag = ((old & 511u) == 511u) ? 1 : 0;
  }
  __syncthreads();
  if (lastFlag) {
    float v = __hip_atomic_load(&partial[t], __ATOMIC_ACQUIRE, __HIP_MEMORY_SCOPE_AGENT) +
              __hip_atomic_load(&partial[t + 256], __ATOMIC_ACQUIRE, __HIP_MEMORY_SCOPE_AGENT);
    for (int off = 32; off; off >>= 1) v += __shfl_down(v, off, 64);
    if ((t & 63) == 0) bsum[t >> 6] = v;  // reuse bsum
    __syncthreads();
    if (t == 0) out[0] = bsum[0] + bsum[1] + bsum[2] + bsum[3];
  }
}

// ---------------- Fallback (tiny ws): self-contained, no scratch ------------
__global__ __launch_bounds__(256) void fallback_kernel(
    const float* __restrict__ R_t, const float* __restrict__ t_t,
    const float* __restrict__ R_p, const float* __restrict__ t_p,
    const float* __restrict__ mp, float* __restrict__ out) {
  __shared__ float4 lds[PP];  // 32 KB
  int blk = blockIdx.x;
  int rc  = blk & 7;
  int dir = (blk >> 3) & 1;
  int b   = blk >> 4;
  const float* Rr = (dir ? R_p : R_t) + b * 9;
  const float* tr_ = (dir ? t_p : t_t) + b * 3;
  const float* Rc = (dir ? R_t : R_p) + b * 9;
  const float* tcp = (dir ? t_t : t_p) + b * 3;
  float c0 = Rc[0], c1 = Rc[1], c2 = Rc[2], c3 = Rc[3], c4 = Rc[4],
        c5 = Rc[5], c6 = Rc[6], c7 = Rc[7], c8 = Rc[8];
  float tc0 = tcp[0], tc1 = tcp[1], tc2 = tcp[2];
  for (int j = threadIdx.x; j < PP; j += 256) {
    int gi = (b * PP + j) * 3;
    float x = mp[gi], y = mp[gi + 1], z = mp[gi + 2];
    float4 q;
    q.x = fmaf(c0, x, fmaf(c1, y, fmaf(c2, z, tc0)));
    q.y = fmaf(c3, x, fmaf(c4, y, fmaf(c5, z, tc1)));
    q.z = fmaf(c6, x, fmaf(c7, y, fmaf(c8, z, tc2)));
    q.w = 0.f;
    lds[j] = q;
  }
  __syncthreads();
  int row = rc * 256 + threadIdx.x;
  int gi = (b * PP + row) * 3;
  float x = mp[gi], y = mp[gi + 1], z = mp[gi + 2];
  float ax = fmaf(Rr[0], x, fmaf(Rr[1], y, fmaf(Rr[2], z, tr_[0])));
  float ay = fmaf(Rr[3], x, fmaf(Rr[4], y, fmaf(Rr[5], z, tr_[1])));
  float az = fmaf(Rr[6], x, fmaf(Rr[7], y, fmaf(Rr[8], z, tr_[2])));
  float m = 3.4e38f;
#pragma unroll 8
  for (int j = 0; j < PP; ++j) {
    float4 q = lds[j];
    float dx = ax - q.x, dy = ay - q.y, dz = az - q.z;
    float d = fmaf(dx, dx, fmaf(dy, dy, dz * dz));
    m = fminf(m, d);
  }
  float v = sqrtf(m + EPSF) * SCALE;
  for (int off = 32; off; off >>= 1) v += __shfl_down(v, off, 64);
  __shared__ float wsum[4];
  if ((threadIdx.x & 63) == 0) wsum[threadIdx.x >> 6] = v;
  __syncthreads();
  if (threadIdx.x == 0) atomicAdd(out, wsum[0] + wsum[1] + wsum[2] + wsum[3]);
}

extern "C" void kernel_launch(void* const* d_in, const int* in_sizes, int n_in,
                              void* d_out, int out_size, void* d_ws, size_t ws_size,
                              hipStream_t stream) {
  const float* R_t = (const float*)d_in[0];
  const float* t_t = (const float*)d_in[1];
  const float* R_p = (const float*)d_in[2];
  const float* t_p = (const float*)d_in[3];
  const float* mp  = (const float*)d_in[4];
  float* out = (float*)d_out;

  if (ws_size >= 512 * sizeof(float) + sizeof(unsigned int)) {
    float* partial = (float*)d_ws;
    unsigned int* cnt = (unsigned int*)(partial + 512);
    pair_mfma_kernel<<<512, 256, 0, stream>>>(R_t, t_t, R_p, t_p, mp,
                                              partial, cnt, out);
  } else {
    hipMemsetAsync(d_out, 0, sizeof(float), stream);
    fallback_kernel<<<256, 256, 0, stream>>>(R_t, t_t, R_p, t_p, mp, out);
  }
}

// Round 16
// 20.597 us; speedup vs baseline: 3.0364x; 1.3527x over previous
//
#include <hip/hip_runtime.h>
#include <math.h>

#define BB 16
#define PP 2048
#define EPSF 1e-8f
#define SCALE (1.0f / (BB * PP))

typedef _Float16 half8 __attribute__((ext_vector_type(8)));
typedef float floatx16 __attribute__((ext_vector_type(16)));

union alignas(16) Pack16 { _Float16 h[16]; float4 v[2]; };

static __device__ __forceinline__ void split16(float x, _Float16& hi, _Float16& lo) {
  hi = (_Float16)x;
  lo = (_Float16)(x - (float)hi);
}

// ---------------- Kernel P: MFMA pairwise min (R12-verified, absmax 0.0) ----
// grid = 512: blk = db(5b)*16 + rowgroup(4b). block = 256 thr = 4 waves.
// Block owns 128 rows (4 strips of 32) x ALL 2048 cols of one (b,dir).
// d^2 = a.Q + qw + aw with Q=-2q, computed exactly (~2^-22) in ONE
// mfma_f32_32x32x16_f16 via K-slot split:
//   A row slots:  [ah x3][ah x3][al x3][1][1][awh][awl][0 x3]
//   B col slots:  [Qh x3][Ql x3][Qh x3][qwh][qwl][1][1][0 x3]
// Both sides use identical (group,j) slot positions -> k-map invariant.
// C orientation irrelevant: dir0+dir1 transpose-symmetric, min-then-sum only.
// LDS frags XOR-swizzled on both write and read sides.
// Lesson ledger: R13 grid.sync = +40us; R14 agent-scope atomic tail = +7us
// (L2 coherence flush per block) -> tiny finish dispatch is the cheapest sync.
__global__ __launch_bounds__(256) void pair_mfma_kernel(
    const float* __restrict__ R_t, const float* __restrict__ t_t,
    const float* __restrict__ R_p, const float* __restrict__ t_p,
    const float* __restrict__ mp, float* __restrict__ partial) {
  __shared__ __align__(16) _Float16 Apack[128 * 16];  // 4 KB
  __shared__ __align__(16) _Float16 Bpack[256 * 16];  // 8 KB
  __shared__ float bsum[8];
  int blk = blockIdx.x;
  int t = threadIdx.x;
  int rg = blk & 15;
  int db = blk >> 4;  // 0..31
  int dir = db & 1, b = db >> 1;
  const float* Rr = (dir ? R_p : R_t) + b * 9;
  const float* trv = (dir ? t_p : t_t) + b * 3;
  const float* Rc = (dir ? R_t : R_p) + b * 9;
  const float* tcv = (dir ? t_t : t_p) + b * 3;

  // --- pack this block's 128 rows (A side) ---
  if (t < 128) {
    int ri = (b << 11) + (rg << 7) + t;
    float x = mp[ri * 3], y = mp[ri * 3 + 1], z = mp[ri * 3 + 2];
    float axf = fmaf(Rr[0], x, fmaf(Rr[1], y, fmaf(Rr[2], z, trv[0])));
    float ayf = fmaf(Rr[3], x, fmaf(Rr[4], y, fmaf(Rr[5], z, trv[1])));
    float azf = fmaf(Rr[6], x, fmaf(Rr[7], y, fmaf(Rr[8], z, trv[2])));
    float awf = fmaf(axf, axf, fmaf(ayf, ayf, azf * azf));
    _Float16 hx, lx, hy, ly, hz, lz, hw, lw;
    split16(axf, hx, lx); split16(ayf, hy, ly); split16(azf, hz, lz);
    split16(awf, hw, lw);
    Pack16 pk;
    pk.h[0] = hx;  pk.h[1] = hy;  pk.h[2] = hz;
    pk.h[3] = hx;  pk.h[4] = hy;  pk.h[5] = hz;
    pk.h[6] = lx;  pk.h[7] = ly;  pk.h[8] = lz;
    pk.h[9] = (_Float16)1.0f; pk.h[10] = (_Float16)1.0f;
    pk.h[11] = hw; pk.h[12] = lw;
    pk.h[13] = (_Float16)0.0f; pk.h[14] = (_Float16)0.0f; pk.h[15] = (_Float16)0.0f;
    int xr = (t >> 2) & 1;
    *(float4*)&Apack[(((t << 1) | 0) ^ xr) * 8] = pk.v[0];
    *(float4*)&Apack[(((t << 1) | 1) ^ xr) * 8] = pk.v[1];
  }

  // prefetch chunk 0 col point
  float ncx, ncy, ncz;
  { int ci = (b << 11) + t; ncx = mp[ci * 3]; ncy = mp[ci * 3 + 1]; ncz = mp[ci * 3 + 2]; }

  __syncthreads();

  int lane = t & 63;
  int wv = t >> 6;        // wave -> 32-row strip
  int cl = lane & 31;
  int g = lane >> 5;      // k-group 0/1 (slots g*8..g*8+7)
  int xorb = (cl >> 2) & 1;
  int rl = (wv << 5) + cl;
  const half8 a_frag = *(const half8*)&Apack[((((rl << 1) | g)) ^ xorb) * 8];
  const _Float16* bbase = &Bpack[(((cl << 1) | g) ^ xorb) * 8];

  float m[16];
#pragma unroll
  for (int r = 0; r < 16; ++r) m[r] = 3.0e38f;
  floatx16 zacc = {};

  for (int c = 0; c < 8; ++c) {
    // pack this chunk's col (1/thread) from prefetched regs (B side)
    {
      float qx = fmaf(Rc[0], ncx, fmaf(Rc[1], ncy, fmaf(Rc[2], ncz, tcv[0])));
      float qy = fmaf(Rc[3], ncx, fmaf(Rc[4], ncy, fmaf(Rc[5], ncz, tcv[1])));
      float qz = fmaf(Rc[6], ncx, fmaf(Rc[7], ncy, fmaf(Rc[8], ncz, tcv[2])));
      float qw = fmaf(qx, qx, fmaf(qy, qy, qz * qz));
      float Qx = -2.f * qx, Qy = -2.f * qy, Qz = -2.f * qz;
      _Float16 hx, lx, hy, ly, hz, lz, hw, lw;
      split16(Qx, hx, lx); split16(Qy, hy, ly); split16(Qz, hz, lz);
      split16(qw, hw, lw);
      Pack16 pk;
      pk.h[0] = hx;  pk.h[1] = hy;  pk.h[2] = hz;
      pk.h[3] = lx;  pk.h[4] = ly;  pk.h[5] = lz;
      pk.h[6] = hx;  pk.h[7] = hy;  pk.h[8] = hz;
      pk.h[9] = hw;  pk.h[10] = lw;
      pk.h[11] = (_Float16)1.0f; pk.h[12] = (_Float16)1.0f;
      pk.h[13] = (_Float16)0.0f; pk.h[14] = (_Float16)0.0f; pk.h[15] = (_Float16)0.0f;
      int xr = (t >> 2) & 1;
      *(float4*)&Bpack[(((t << 1) | 0) ^ xr) * 8] = pk.v[0];
      *(float4*)&Bpack[(((t << 1) | 1) ^ xr) * 8] = pk.v[1];
    }
    __syncthreads();  // B ready
    if (c < 7) {      // prefetch next chunk under compute
      int ci = (b << 11) + ((c + 1) << 8) + t;
      ncx = mp[ci * 3]; ncy = mp[ci * 3 + 1]; ncz = mp[ci * 3 + 2];
    }
#pragma unroll
    for (int ct = 0; ct < 8; ct += 2) {
      half8 b0 = *(const half8*)(bbase + ct * 512);        // +1024B/tile, swizzle-consistent
      half8 b1 = *(const half8*)(bbase + (ct + 1) * 512);
      floatx16 acc0 = __builtin_amdgcn_mfma_f32_32x32x16_f16(a_frag, b0, zacc, 0, 0, 0);
      floatx16 acc1 = __builtin_amdgcn_mfma_f32_32x32x16_f16(a_frag, b1, zacc, 0, 0, 0);
#pragma unroll
      for (int r = 0; r < 16; ++r)
        m[r] = fminf(fminf(m[r], acc0[r]), acc1[r]);       // v_min3_f32
    }
    __syncthreads();  // chunk consumed
  }

  // min across the 32 lanes sharing g (bits 0..4) -> per-(hi,reg) row mins
#pragma unroll
  for (int mask = 1; mask <= 16; mask <<= 1)
#pragma unroll
    for (int r = 0; r < 16; ++r) m[r] = fminf(m[r], __shfl_xor(m[r], mask, 64));

  float s = 0.f;
#pragma unroll
  for (int r = 0; r < 16; ++r) s += sqrtf(fmaxf(m[r], 0.f) + EPSF);
  if (cl == 0) bsum[(wv << 1) | g] = s;
  __syncthreads();
  if (t == 0) {
    float tot = 0.f;
#pragma unroll
    for (int i = 0; i < 8; ++i) tot += bsum[i];
    partial[blk] = tot * SCALE;
  }
}

// ---------------- Kernel F: sum 512 block partials ----------------
__global__ __launch_bounds__(256) void finish_kernel(
    const float* __restrict__ partial, float* __restrict__ out) {
  int t = threadIdx.x;
  float v = partial[t] + partial[t + 256];
  for (int off = 32; off; off >>= 1) v += __shfl_down(v, off, 64);
  __shared__ float ws4[4];
  if ((t & 63) == 0) ws4[t >> 6] = v;
  __syncthreads();
  if (t == 0) out[0] = ws4[0] + ws4[1] + ws4[2] + ws4[3];
}

// ---------------- Fallback (tiny ws): self-contained, no scratch ------------
__global__ __launch_bounds__(256) void fallback_kernel(
    const float* __restrict__ R_t, const float* __restrict__ t_t,
    const float* __restrict__ R_p, const float* __restrict__ t_p,
    const float* __restrict__ mp, float* __restrict__ out) {
  __shared__ float4 lds[PP];  // 32 KB
  int blk = blockIdx.x;
  int rc  = blk & 7;
  int dir = (blk >> 3) & 1;
  int b   = blk >> 4;
  const float* Rr = (dir ? R_p : R_t) + b * 9;
  const float* tr_ = (dir ? t_p : t_t) + b * 3;
  const float* Rc = (dir ? R_t : R_p) + b * 9;
  const float* tcp = (dir ? t_t : t_p) + b * 3;
  float c0 = Rc[0], c1 = Rc[1], c2 = Rc[2], c3 = Rc[3], c4 = Rc[4],
        c5 = Rc[5], c6 = Rc[6], c7 = Rc[7], c8 = Rc[8];
  float tc0 = tcp[0], tc1 = tcp[1], tc2 = tcp[2];
  for (int j = threadIdx.x; j < PP; j += 256) {
    int gi = (b * PP + j) * 3;
    float x = mp[gi], y = mp[gi + 1], z = mp[gi + 2];
    float4 q;
    q.x = fmaf(c0, x, fmaf(c1, y, fmaf(c2, z, tc0)));
    q.y = fmaf(c3, x, fmaf(c4, y, fmaf(c5, z, tc1)));
    q.z = fmaf(c6, x, fmaf(c7, y, fmaf(c8, z, tc2)));
    q.w = 0.f;
    lds[j] = q;
  }
  __syncthreads();
  int row = rc * 256 + threadIdx.x;
  int gi = (b * PP + row) * 3;
  float x = mp[gi], y = mp[gi + 1], z = mp[gi + 2];
  float ax = fmaf(Rr[0], x, fmaf(Rr[1], y, fmaf(Rr[2], z, tr_[0])));
  float ay = fmaf(Rr[3], x, fmaf(Rr[4], y, fmaf(Rr[5], z, tr_[1])));
  float az = fmaf(Rr[6], x, fmaf(Rr[7], y, fmaf(Rr[8], z, tr_[2])));
  float m = 3.4e38f;
#pragma unroll 8
  for (int j = 0; j < PP; ++j) {
    float4 q = lds[j];
    float dx = ax - q.x, dy = ay - q.y, dz = az - q.z;
    float d = fmaf(dx, dx, fmaf(dy, dy, dz * dz));
    m = fminf(m, d);
  }
  float v = sqrtf(m + EPSF) * SCALE;
  for (int off = 32; off; off >>= 1) v += __shfl_down(v, off, 64);
  __shared__ float wsum[4];
  if ((threadIdx.x & 63) == 0) wsum[threadIdx.x >> 6] = v;
  __syncthreads();
  if (threadIdx.x == 0) atomicAdd(out, wsum[0] + wsum[1] + wsum[2] + wsum[3]);
}

extern "C" void kernel_launch(void* const* d_in, const int* in_sizes, int n_in,
                              void* d_out, int out_size, void* d_ws, size_t ws_size,
                              hipStream_t stream) {
  const float* R_t = (const float*)d_in[0];
  const float* t_t = (const float*)d_in[1];
  const float* R_p = (const float*)d_in[2];
  const float* t_p = (const float*)d_in[3];
  const float* mp  = (const float*)d_in[4];
  float* out = (float*)d_out;

  if (ws_size >= 512 * sizeof(float)) {
    float* partial = (float*)d_ws;
    pair_mfma_kernel<<<512, 256, 0, stream>>>(R_t, t_t, R_p, t_p, mp, partial);
    finish_kernel<<<1, 256, 0, stream>>>(partial, out);
  } else {
    hipMemsetAsync(d_out, 0, sizeof(float), stream);
    fallback_kernel<<<256, 256, 0, stream>>>(R_t, t_t, R_p, t_p, mp, out);
  }
}